// Round 5
// baseline (43.545 us; speedup 1.0000x reference)
//
#include <hip/hip_runtime.h>

#define BATCH  16384
#define NFEAT  50
#define DIM    128
#define G      10   // staged loads per group (x2 tables = 20 float4 in flight)
#define NG     5    // NFEAT / G

// One wave = 2 batch elements (lanes 0-31 -> b0, 32-63 -> b1), lane owns 4 dims.
// Feature loop is software-pipelined in register groups: all 2*G float4 gathers
// of a group are issued back-to-back into distinct registers BEFORE any consume,
// giving ~20 outstanding loads/wave (vs ~4 when the compiler minimizes VGPRs).
__global__ __launch_bounds__(256, 4) void mf_dot_mlp(
    const int*   __restrict__ user_ids,
    const int*   __restrict__ item_ids,
    const int*   __restrict__ ufi,
    const float* __restrict__ ufv,
    const int*   __restrict__ ifi,
    const float* __restrict__ ifv,
    const float* __restrict__ user_emb,
    const float* __restrict__ item_emb,
    const float* __restrict__ ufe,
    const float* __restrict__ ife,
    float*       __restrict__ out)
{
    const int tid  = threadIdx.x;
    const int lane = tid & 63;
    const int half = lane >> 5;
    const int sl   = lane & 31;
    const int d0   = sl * 4;

    int wv = (int)((blockIdx.x * blockDim.x + tid) >> 6);
    wv = __builtin_amdgcn_readfirstlane(wv);
    const int b0 = wv * 2, b1 = b0 + 1;
    const int b  = half ? b1 : b0;

    const int uid0 = user_ids[b0], uid1 = user_ids[b1];
    const int iid0 = item_ids[b0], iid1 = item_ids[b1];
    const int urow = half ? uid1 : uid0;
    const int irow = half ? iid1 : iid0;

    // Issue the high-latency (L3-resident) id-embedding loads FIRST;
    // they are consumed only after the feature loop.
    const float4 u0 = *reinterpret_cast<const float4*>(user_emb + (size_t)urow * DIM + d0);
    const float4 v0 = *reinterpret_cast<const float4*>(item_emb + (size_t)irow * DIM + d0);

    const int*   __restrict__ ufi0 = ufi + (size_t)b0 * NFEAT;
    const int*   __restrict__ ufi1 = ufi + (size_t)b1 * NFEAT;
    const float* __restrict__ ufv0 = ufv + (size_t)b0 * NFEAT;
    const float* __restrict__ ufv1 = ufv + (size_t)b1 * NFEAT;
    const int*   __restrict__ ifi0 = ifi + (size_t)b0 * NFEAT;
    const int*   __restrict__ ifi1 = ifi + (size_t)b1 * NFEAT;
    const float* __restrict__ ifv0 = ifv + (size_t)b0 * NFEAT;
    const float* __restrict__ ifv1 = ifv + (size_t)b1 * NFEAT;

    const float* __restrict__ ubase = ufe + d0;
    const float* __restrict__ ibase = ife + d0;

    float4 uacc = make_float4(0.f, 0.f, 0.f, 0.f);
    float4 vacc = make_float4(0.f, 0.f, 0.f, 0.f);

    #pragma unroll
    for (int grp = 0; grp < NG; ++grp) {
        float4 su[G], si[G];
        float  uw[G], iw[G];

        // Phase 1: issue all 2*G gathers into distinct registers.
        #pragma unroll
        for (int g = 0; g < G; ++g) {
            const int f  = grp * G + g;
            const int ur = half ? ufi1[f] : ufi0[f];
            const int ir = half ? ifi1[f] : ifi0[f];
            uw[g] = half ? ufv1[f] : ufv0[f];
            iw[g] = half ? ifv1[f] : ifv0[f];
            su[g] = *reinterpret_cast<const float4*>(ubase + (size_t)ur * DIM);
            si[g] = *reinterpret_cast<const float4*>(ibase + (size_t)ir * DIM);
        }

        // Phase 2: consume.
        #pragma unroll
        for (int g = 0; g < G; ++g) {
            uacc.x = fmaf(uw[g], su[g].x, uacc.x);
            uacc.y = fmaf(uw[g], su[g].y, uacc.y);
            uacc.z = fmaf(uw[g], su[g].z, uacc.z);
            uacc.w = fmaf(uw[g], su[g].w, uacc.w);
            vacc.x = fmaf(iw[g], si[g].x, vacc.x);
            vacc.y = fmaf(iw[g], si[g].y, vacc.y);
            vacc.z = fmaf(iw[g], si[g].z, vacc.z);
            vacc.w = fmaf(iw[g], si[g].w, vacc.w);
        }
    }

    const float ux = uacc.x + u0.x, uy = uacc.y + u0.y;
    const float uz = uacc.z + u0.z, uwd = uacc.w + u0.w;
    const float vx = vacc.x + v0.x, vy = vacc.y + v0.y;
    const float vz = vacc.z + v0.z, vwd = vacc.w + v0.w;

    float dot = ux * vx + uy * vy + uz * vz + uwd * vwd;

    #pragma unroll
    for (int off = 16; off > 0; off >>= 1)
        dot += __shfl_xor(dot, off);

    if (sl == 0) out[b] = dot;
}

extern "C" void kernel_launch(void* const* d_in, const int* in_sizes, int n_in,
                              void* d_out, int out_size, void* d_ws, size_t ws_size,
                              hipStream_t stream) {
    const int*   user_ids      = (const int*)  d_in[0];
    const int*   item_ids      = (const int*)  d_in[1];
    const int*   ufi           = (const int*)  d_in[2];
    const float* ufv           = (const float*)d_in[3];
    const int*   ifi           = (const int*)  d_in[4];
    const float* ifv           = (const float*)d_in[5];
    const float* user_emb      = (const float*)d_in[6];
    const float* item_emb      = (const float*)d_in[7];
    const float* user_feat_emb = (const float*)d_in[8];
    const float* item_feat_emb = (const float*)d_in[9];
    float* out = (float*)d_out;

    // 2 elements/wave, 4 waves/block -> 8 elements/block.
    mf_dot_mlp<<<BATCH / 8, 256, 0, stream>>>(
        user_ids, item_ids, ufi, ufv, ifi, ifv,
        user_emb, item_emb, user_feat_emb, item_feat_emb, out);
}